// Round 7
// baseline (428.919 us; speedup 1.0000x reference)
//
#include <hip/hip_runtime.h>
#include <stdint.h>
#include <math.h>

#define DIMC 2048
#define NHEADS 16
#define HDIM 128
#define TSEQ 2048
#define NTOK 4096   // B*T

using bf16x8 = __attribute__((ext_vector_type(8))) short;
using f32x4  = __attribute__((ext_vector_type(4))) float;

typedef __attribute__((address_space(1))) const void gas_void;
typedef __attribute__((address_space(3))) void las_void;

static __device__ __forceinline__ unsigned short f2b(float f) {
  union { float f; unsigned int u; } a; a.f = f;
  unsigned int u = a.u;
  u = (u + 0x7fffu + ((u >> 16) & 1u)) >> 16;   // RNE
  return (unsigned short)u;
}
static __device__ __forceinline__ float b2f(unsigned short s) {
  union { unsigned int u; float f; } a; a.u = ((unsigned int)s) << 16;
  return a.f;
}

// wave-uniform input dtype detect (bf16 vs fp32) from x's first 128 shorts.
static __device__ __forceinline__ int detect_inline(const void* __restrict__ x)
{
  const int lane = threadIdx.x & 63;
  const unsigned short u = ((const unsigned short*)x)[2 * lane];
  const int e = (u >> 7) & 0xFF;
  const unsigned long long m = __ballot((e >= 112) && (e <= 135));
  return (__popcll(m) >= 32) ? 1 : 0;
}

// ---------------- ternary dequant core (dtype-flag branched) --------------
// Threshold test via multiply: wn>0.5 <=> a>0.5*scale (0.5*scale is exact
// in FP, so this is the exact real-arithmetic comparison — no f64 divides).
static __device__ __forceinline__ void dequant_one(
    const void* __restrict__ w, unsigned short* __restrict__ o,
    int grp, int lane, int isbf16)
{
  float a, bq;
  if (isbf16) {
    const unsigned int pk =
        ((const unsigned int*)((const unsigned short*)w + (long)grp * 128))[lane];
    a  = b2f((unsigned short)(pk & 0xffffu));
    bq = b2f((unsigned short)(pk >> 16));
  } else {
    const float2 v = ((const float2*)((const float*)w + (long)grp * 128))[lane];
    a = v.x; bq = v.y;
  }
  double s = fabs((double)a) + fabs((double)bq);
  #pragma unroll
  for (int off = 1; off < 64; off <<= 1) s += __shfl_xor(s, off);
  double scale = s * (1.0 / 128.0);
  if (scale < 1e-8) scale = 1e-8;
  const float fs = (float)scale;
  const double hs = 0.5 * scale;
  const double da = (double)a, db = (double)bq;
  const float q0 = (da > hs) ? fs : ((da < -hs) ? -fs : 0.0f);
  const float q1 = (db > hs) ? fs : ((db < -hs) ? -fs : 0.0f);
  const unsigned int opk = (unsigned int)f2b(q0) | ((unsigned int)f2b(q1) << 16);
  ((unsigned int*)o)[(long)grp * 64 + lane] = opk;
}

// fused prep: y=0 cast x->bf16; y=1..3 dequant wq/wk/wv into row-stacked
// [6144][2048]; y=4 (only when ws has room) dequant wo into its own buffer.
__global__ void __launch_bounds__(256) prep(
    const void* __restrict__ x,
    const void* __restrict__ w0, const void* __restrict__ w1,
    const void* __restrict__ w2, const void* __restrict__ w3,
    unsigned short* __restrict__ xb, unsigned short* __restrict__ wqkv,
    unsigned short* __restrict__ wob)
{
  const int isbf16 = detect_inline(x);
  const int wave = threadIdx.x >> 6, lane = threadIdx.x & 63;
  const int y = blockIdx.y;
  if (y == 0) {
    const int i = (blockIdx.x * 256 + threadIdx.x) * 4;
    if (isbf16) {
      *(ushort4*)(xb + i) = *(const ushort4*)((const unsigned short*)x + i);
    } else {
      const float4 v = *(const float4*)((const float*)x + i);
      ushort4 u;
      u.x = f2b(v.x); u.y = f2b(v.y); u.z = f2b(v.z); u.w = f2b(v.w);
      *(ushort4*)(xb + i) = u;
    }
  } else if (y <= 3) {
    const void* w = (y == 1) ? w0 : (y == 2) ? w1 : w2;
    dequant_one(w, wqkv + (long)(y - 1) * DIMC * DIMC,
                blockIdx.x * 4 + wave, lane, isbf16);
  } else {
    dequant_one(w3, wob, blockIdx.x * 4 + wave, lane, isbf16);
  }
}

// fallback wo-dequant (inline flag) when ws can't host a separate wo buffer
__global__ void __launch_bounds__(256) dequant_auto(
    const void* __restrict__ w, const void* __restrict__ x,
    unsigned short* __restrict__ o)
{
  const int isbf16 = detect_inline(x);
  dequant_one(w, o, blockIdx.x * 4 + (threadIdx.x >> 6), threadIdx.x & 63,
              isbf16);
}

// ========== 256x128-tile 8-wave 2-phase-per-K GEMM (swizzled LDS) =========
// See R6 notes: 768 blocks = 3.0 clean rounds, bank-conflict 0, 853 TF.
// Schedule per K-tile t:
//  ph1: 16 ds_reads | stage A(t+1)->nxt | BAR | lgkm0 | 16 MFMA | BAR
//  ph2: stage B(t+2)->cur | 16 MFMA | vmcnt(2) | BAR   (never drains to 0)
static __device__ __forceinline__ void gemm8_core(
    const unsigned short* __restrict__ A, const unsigned short* __restrict__ Bm,
    int m0, int n0, int K, f32x4 (&acc)[4][4],
    unsigned short (*sm)[3][8192])
{
  const int tid = threadIdx.x;
  const int w = tid >> 6, lane = tid & 63;
  const int wr = w >> 1, wc = w & 1;
  const int c16 = lane & 15, q4 = lane >> 4;
  const int swz = (c16 * 32 + q4 * 8) ^ ((c16 & 8) ? 16 : 0);
  const int srow = lane >> 2;
  const int scol = ((lane & 3) * 8) ^ ((lane & 32) ? 16 : 0);
  const int rg0 = w >> 1, cg = w & 1;
  const int NT = K >> 6;

  #pragma unroll
  for (int i = 0; i < 4; i++)
    #pragma unroll
    for (int j = 0; j < 4; j++) acc[i][j] = (f32x4){0.f, 0.f, 0.f, 0.f};

  auto stage = [&](const unsigned short* __restrict__ G, int rowbase, int kt,
                   unsigned short* dst) {
    #pragma unroll
    for (int l = 0; l < 2; l++) {
      const unsigned short* s = G +
          (long)(rowbase + (rg0 + l * 4) * 16 + srow) * K + kt * 64 + cg * 32 + scol;
      __builtin_amdgcn_global_load_lds((gas_void*)s,
          (las_void*)(dst + (l * 8 + w) * 512), 16, 0, 0);
    }
  };

  // prologue: t0 {A0,A1,B} -> parity0 ; B(1) -> parity1
  stage(A,  m0,       0, sm[0][0]);
  stage(A,  m0 + 128, 0, sm[0][1]);
  stage(Bm, n0,       0, sm[0][2]);
  stage(Bm, n0,       1, sm[1][2]);
  asm volatile("s_waitcnt vmcnt(2)" ::: "memory");
  __builtin_amdgcn_s_barrier();

  bf16x8 af[4][2], b01[2][2], b23[2][2];
  const int ah = wr >> 1;               // which A half (0: rows<128)
  const int abase = (wr & 1) * 4096;    // 4 subtiles into that half
  const int bbase = wc * 4096;          // B cols wc*64

  for (int t = 0; t < NT; ++t) {
    const int cur = t & 1, nxt = cur ^ 1;

    // -------- phase 1 --------
    #pragma unroll
    for (int m = 0; m < 4; m++)
      #pragma unroll
      for (int kk = 0; kk < 2; kk++)
        af[m][kk] = *(const bf16x8*)&sm[cur][ah][abase + m * 1024 + kk * 512 + swz];
    #pragma unroll
    for (int n = 0; n < 2; n++)
      #pragma unroll
      for (int kk = 0; kk < 2; kk++) {
        b01[n][kk] = *(const bf16x8*)&sm[cur][2][bbase + n * 1024 + kk * 512 + swz];
        b23[n][kk] = *(const bf16x8*)&sm[cur][2][bbase + (2 + n) * 1024 + kk * 512 + swz];
      }
    if (t + 1 < NT) {
      stage(A, m0,       t + 1, sm[nxt][0]);
      stage(A, m0 + 128, t + 1, sm[nxt][1]);
    }
    __builtin_amdgcn_s_barrier();
    asm volatile("s_waitcnt lgkmcnt(0)" ::: "memory");
    __builtin_amdgcn_s_setprio(1);
    #pragma unroll
    for (int kk = 0; kk < 2; kk++)
      #pragma unroll
      for (int m = 0; m < 4; m++)
        #pragma unroll
        for (int n = 0; n < 2; n++)
          acc[m][n] = __builtin_amdgcn_mfma_f32_16x16x32_bf16(
              af[m][kk], b01[n][kk], acc[m][n], 0, 0, 0);
    __builtin_amdgcn_s_setprio(0);
    __builtin_amdgcn_s_barrier();

    // -------- phase 2 --------
    if (t + 2 < NT) stage(Bm, n0, t + 2, sm[cur][2]);
    __builtin_amdgcn_s_setprio(1);
    #pragma unroll
    for (int kk = 0; kk < 2; kk++)
      #pragma unroll
      for (int m = 0; m < 4; m++)
        #pragma unroll
        for (int n = 0; n < 2; n++)
          acc[m][2 + n] = __builtin_amdgcn_mfma_f32_16x16x32_bf16(
              af[m][kk], b23[n][kk], acc[m][2 + n], 0, 0, 0);
    __builtin_amdgcn_s_setprio(0);
    if (t + 1 < NT) {
      if (t + 2 < NT) { asm volatile("s_waitcnt vmcnt(2)" ::: "memory"); }
      else            { asm volatile("s_waitcnt vmcnt(0)" ::: "memory"); }
      __builtin_amdgcn_s_barrier();
    }
  }
}

// QKV: B row-stacked [6144][2048]; 128-col slab = exactly one head.
// Grid TRANSPOSED (x = m-tile fastest): a dispatch round covers a balanced
// 16x16 tile square (24MB unique, 16x panel reuse) instead of 48x5.3.
// RoPE fused into the epilogue for Q/K slabs: (d,d+64) pair lives in the
// partner wc-wave -> exchange f32 acc tile via LDS in 4 mt-chunks (32KB,
// reusing sm), rope on f32 (one fewer bf16 rounding), store bf16.
__global__ void __launch_bounds__(512, 2) gemm8_qkv(
    const unsigned short* __restrict__ A, const unsigned short* __restrict__ Bm,
    unsigned short* __restrict__ C0, unsigned short* __restrict__ C1,
    unsigned short* __restrict__ C2, int K)
{
  __shared__ unsigned short sm[2][3][8192];   // 96 KB
  const int m0 = blockIdx.x * 256;            // x = m-tile (fastest)
  const int n0 = blockIdx.y * 128;            // y = n-slab 0..47
  f32x4 acc[4][4];
  gemm8_core(A, Bm, m0, n0, K, acc, sm);

  unsigned short* Cb = (n0 < 2048) ? C0 : (n0 < 4096) ? C1 : C2;
  const int w = threadIdx.x >> 6, lane = threadIdx.x & 63;
  const int wr = w >> 1, wc = w & 1;
  const int c16 = lane & 15, q4 = lane >> 4;
  const int nloc = (n0 & 2047) + wc * 64;

  if (n0 < 4096) {
    // fused RoPE (Q and K slabs)
    float* stg = (float*)&sm[0][0][0];        // 8 waves x 1024 f32 = 32 KB
    const int pw = wr * 2 + (wc ^ 1);         // partner wave (other half)
    __syncthreads();                          // K-loop LDS reads fully done
    for (int mt = 0; mt < 4; mt++) {
      #pragma unroll
      for (int nt = 0; nt < 4; nt++)
        #pragma unroll
        for (int r = 0; r < 4; r++)
          stg[w * 1024 + (q4 * 4 + r) * 64 + nt * 16 + c16] = acc[mt][nt][r];
      __syncthreads();
      #pragma unroll
      for (int nt = 0; nt < 4; nt++) {
        const int d = nt * 16 + c16;          // 0..63 within half
        const float inv_freq =
            expf(-9.210340371976184f * (float)d * (1.0f / 64.0f));
        #pragma unroll
        for (int r = 0; r < 4; r++) {
          const int m = m0 + wr * 64 + mt * 16 + q4 * 4 + r;
          float sn, cs;
          sincosf((float)(m & (TSEQ - 1)) * inv_freq, &sn, &cs);
          const float other = stg[pw * 1024 + (q4 * 4 + r) * 64 + d];
          const float own = acc[mt][nt][r];
          // wc=0 holds x1 (d<64): out = x1*cs - x2*sn
          // wc=1 holds x2 (d>=64): out = x1*sn + x2*cs
          const float outv = (wc == 0) ? (own * cs - other * sn)
                                       : (other * sn + own * cs);
          Cb[(long)m * DIMC + nloc + d] = f2b(outv);
        }
      }
      __syncthreads();                        // readers done before next mt
    }
  } else {
    // V slab: plain bf16 store (C/D layout: n=lane&15, m=(lane>>4)*4+reg)
    #pragma unroll
    for (int mt = 0; mt < 4; mt++) {
      const int m = m0 + wr * 64 + mt * 16 + q4 * 4;
      #pragma unroll
      for (int nt = 0; nt < 4; nt++) {
        const int n = nloc + nt * 16 + c16;
        #pragma unroll
        for (int r = 0; r < 4; r++)
          Cb[(long)(m + r) * DIMC + n] = f2b(acc[mt][nt][r]);
      }
    }
  }
}

// wo projection: fp32 output, direct [4096][2048] (256 blocks = 1.0 round)
__global__ void __launch_bounds__(512, 2) gemm8_bt(
    const unsigned short* __restrict__ A, const unsigned short* __restrict__ Bm,
    float* __restrict__ C, int N, int K)
{
  __shared__ unsigned short sm[2][3][8192];   // 96 KB
  const int n0 = blockIdx.x * 128;
  const int m0 = blockIdx.y * 256;
  f32x4 acc[4][4];
  gemm8_core(A, Bm, m0, n0, K, acc, sm);

  const int w = threadIdx.x >> 6, lane = threadIdx.x & 63;
  const int wr = w >> 1, wc = w & 1;
  const int c16 = lane & 15, q4 = lane >> 4;
  #pragma unroll
  for (int mt = 0; mt < 4; mt++) {
    const int m = m0 + wr * 64 + mt * 16 + q4 * 4;
    #pragma unroll
    for (int nt = 0; nt < 4; nt++) {
      const int n = n0 + wc * 64 + nt * 16 + c16;
      #pragma unroll
      for (int r = 0; r < 4; r++)
        C[(long)(m + r) * N + n] = acc[mt][nt][r];
    }
  }
}

// ---------------- flash attention v3 (causal), bf16 MFMA ----------------
// EXACT round-0 version (best-measured state; R2/R3 variants regressed).
#define FA_M 16.0f
__global__ void __launch_bounds__(256) fattn(
    const unsigned short* __restrict__ Q,
    const unsigned short* __restrict__ K,
    const unsigned short* __restrict__ V,
    unsigned short* __restrict__ Y)
{
  __shared__ unsigned short SU[9216];       // 18432 B union (Ks | Ps)
  __shared__ unsigned short VT[128 * 72];   // 18432 B
  __shared__ float red[4][32];

  const int tid = threadIdx.x, wave = tid >> 6, lane = tid & 63;
  const int idx = blockIdx.x;               // 512 blocks
  const int qt = 15 - (idx >> 5);           // heaviest (qt=15) first
  const int bh = idx & 31;
  const int b = bh >> 4, h = bh & 15;
  const int qbase = qt * 128;
  const int qw = wave * 32;
  const int c = lane & 15, g = lane >> 4;
  const long tokbase = (long)b * TSEQ;
  const int col0 = h * HDIM;

  bf16x8 qf[2][4];
  #pragma unroll
  for (int qq = 0; qq < 2; qq++) {
    const unsigned short* qp =
        Q + (tokbase + qbase + qw + qq * 16 + c) * DIMC + col0 + g * 8;
    #pragma unroll
    for (int kc = 0; kc < 4; kc++) qf[qq][kc] = *(const bf16x8*)(qp + kc * 32);
  }

  f32x4 od[8][2];
  #pragma unroll
  for (int dt = 0; dt < 8; dt++)
    #pragma unroll
    for (int qq = 0; qq < 2; qq++)
      od[dt][qq] = (f32x4){0.f, 0.f, 0.f, 0.f};
  float lpart[2][4];
  #pragma unroll
  for (int qq = 0; qq < 2; qq++)
    #pragma unroll
    for (int r = 0; r < 4; r++) lpart[qq][r] = 0.0f;

  const int ksr = tid >> 2, ksc = (tid & 3) * 32;
  const int vk0 = (tid & 31) * 2, vd0 = (tid >> 5) * 16;

  const float SC = 0.088388347648318447f;  // 1/sqrt(128)
  const int nkt = 2 * qt + 2;

  // prefetch registers (K row chunk: 4x float4; V: 2 keys x 16 d)
  float4 kr0, kr1, kr2, kr3;
  bf16x8 va0, va1, vb0, vb1;
  {
    const unsigned short* src = K + (tokbase + ksr) * DIMC + col0 + ksc;
    kr0 = ((const float4*)src)[0]; kr1 = ((const float4*)src)[1];
    kr2 = ((const float4*)src)[2]; kr3 = ((const float4*)src)[3];
    const unsigned short* s0 = V + (tokbase + vk0) * DIMC + col0 + vd0;
    const unsigned short* s1 = s0 + DIMC;
    va0 = *(const bf16x8*)(s0); va1 = *(const bf16x8*)(s0 + 8);
    vb0 = *(const bf16x8*)(s1); vb1 = *(const bf16x8*)(s1 + 8);
  }

  for (int kt = 0; kt < nkt; kt++) {
    const int kb = kt * 64;
    __syncthreads();   // A: prev-iter readers done with SU/VT
    {
      float4* dst = (float4*)&SU[ksr * 136 + ksc];
      dst[0] = kr0; dst[1] = kr1; dst[2] = kr2; dst[3] = kr3;
    }
    {
      #pragma unroll
      for (int dd = 0; dd < 8; dd++) {
        const unsigned int p0 =
            (unsigned int)(unsigned short)va0[dd] |
            ((unsigned int)(unsigned short)vb0[dd] << 16);
        *(unsigned int*)&VT[(vd0 + dd) * 72 + vk0] = p0;
      }
      #pragma unroll
      for (int dd = 0; dd < 8; dd++) {
        const unsigned int p1 =
            (unsigned int)(unsigned short)va1[dd] |
            ((unsigned int)(unsigned short)vb1[dd] << 16);
        *(unsigned int*)&VT[(vd0 + 8 + dd) * 72 + vk0] = p1;
      }
    }
    __syncthreads();   // B: staging visible

    if (kt + 1 < nkt) {   // issue next tile's loads; consumed at next barrier A
      const int kb2 = kb + 64;
      const unsigned short* src = K + (tokbase + kb2 + ksr) * DIMC + col0 + ksc;
      kr0 = ((const float4*)src)[0]; kr1 = ((const float4*)src)[1];
      kr2 = ((const float4*)src)[2]; kr3 = ((const float4*)src)[3];
      const unsigned short* s0 = V + (tokbase + kb2 + vk0) * DIMC + col0 + vd0;
      const unsigned short* s1 = s0 + DIMC;
      va0 = *(const bf16x8*)(s0); va1 = *(const bf16x8*)(s0 + 8);
      vb0 = *(const bf16x8*)(s1); vb1 = *(const bf16x8*)(s1 + 8);
    }

    f32x4 sacc[2][4];
    #pragma unroll
    for (int qq = 0; qq < 2; qq++)
      #pragma unroll
      for (int nt = 0; nt < 4; nt++) sacc[qq][nt] = (f32x4){0.f, 0.f, 0.f, 0.f};
    #pragma unroll
    for (int kc = 0; kc < 4; kc++) {
      bf16x8 bk[4];
      #pragma unroll
      for (int nt = 0; nt < 4; nt++)
        bk[nt] = *(const bf16x8*)&SU[(nt * 16 + c) * 136 + kc * 32 + g * 8];
      #pragma unroll
      for (int qq = 0; qq < 2; qq++)
        #pragma unroll
        for (int nt = 0; nt < 4; nt++)
          sacc[qq][nt] = __builtin_amdgcn_mfma_f32_16x16x32_bf16(
              qf[qq][kc], bk[nt], sacc[qq][nt], 0, 0, 0);
    }
    __syncthreads();   // C: Ks reads done before Ps overwrites SU

    #pragma unroll
    for (int qq = 0; qq < 2; qq++)
      #pragma unroll
      for (int r = 0; r < 4; r++) {
        const int qg = qbase + qw + qq * 16 + g * 4 + r;
        #pragma unroll
        for (int nt = 0; nt < 4; nt++) {
          const int kg = kb + nt * 16 + c;
          const float sv = sacc[qq][nt][r] * SC - FA_M;
          const float p = (kg > qg) ? 0.0f : __expf(sv);
          lpart[qq][r] += p;
          SU[(wave * 32 + qq * 16 + g * 4 + r) * 72 + nt * 16 + c] = f2b(p);
        }
      }

    #pragma unroll
    for (int kc = 0; kc < 2; kc++) {
      bf16x8 pb[2];
      #pragma unroll
      for (int qq = 0; qq < 2; qq++)
        pb[qq] = *(const bf16x8*)&SU[(wave * 32 + qq * 16 + c) * 72 + kc * 32 + g * 8];
      #pragma unroll
      for (int dt = 0; dt < 8; dt++) {
        bf16x8 va = *(const bf16x8*)&VT[(dt * 16 + c) * 72 + kc * 32 + g * 8];
        #pragma unroll
        for (int qq = 0; qq < 2; qq++)
          od[dt][qq] = __builtin_amdgcn_mfma_f32_16x16x32_bf16(
              va, pb[qq], od[dt][qq], 0, 0, 0);
      }
    }
  }

  #pragma unroll
  for (int qq = 0; qq < 2; qq++)
    #pragma unroll
    for (int r = 0; r < 4; r++) {
      float l = lpart[qq][r];
      #pragma unroll
      for (int off = 1; off < 16; off <<= 1) l += __shfl_xor(l, off);
      lpart[qq][r] = l;
    }
  __syncthreads();
  if (c == 0) {
    #pragma unroll
    for (int qq = 0; qq < 2; qq++)
      #pragma unroll
      for (int r = 0; r < 4; r++)
        red[wave][qq * 16 + g * 4 + r] = 1.0f / lpart[qq][r];
  }
  __syncthreads();
  #pragma unroll
  for (int qq = 0; qq < 2; qq++) {
    const float linv = red[wave][qq * 16 + c];
    unsigned short* yp =
        Y + (tokbase + qbase + qw + qq * 16 + c) * DIMC + col0;
    #pragma unroll
    for (int dt = 0; dt < 8; dt++)
      #pragma unroll
      for (int r = 0; r < 4; r++)
        yp[dt * 16 + g * 4 + r] = f2b(od[dt][qq][r] * linv);
  }
}

extern "C" void kernel_launch(void* const* d_in, const int* in_sizes, int n_in,
                              void* d_out, int out_size, void* d_ws, size_t ws_size,
                              hipStream_t stream)
{
  const void* x  = d_in[0];
  const void* wq = d_in[1];
  const void* wk = d_in[2];
  const void* wv = d_in[3];
  const void* wo = d_in[4];
  float* out = (float*)d_out;

  char* ws = (char*)d_ws;
  const size_t MB = 1024 * 1024;
  unsigned short* wbuf = (unsigned short*)(ws + 0 * MB);   // 24 MB (QKV stacked)
  unsigned short* xb   = (unsigned short*)(ws + 24 * MB);  // 16 MB
  unsigned short* Qb   = (unsigned short*)(ws + 40 * MB);  // 16 MB
  unsigned short* Kb   = (unsigned short*)(ws + 56 * MB);  // 16 MB
  unsigned short* Vb   = (unsigned short*)(ws + 72 * MB);  // 16 MB
  unsigned short* wob  = (unsigned short*)(ws + 88 * MB);  // 8 MB (if room)
  unsigned short* Yb   = xb;   // x dead after QKV projection; alias.

  const int wo_in_prep = (ws_size >= 97 * MB) ? 1 : 0;

  prep<<<dim3(8192, wo_in_prep ? 5 : 4), 256, 0, stream>>>(
      x, wq, wk, wv, wo, xb, wbuf, wob);
  gemm8_qkv<<<dim3(16, 48), 512, 0, stream>>>(xb, wbuf, Qb, Kb, Vb, DIMC);
  fattn<<<dim3(512), 256, 0, stream>>>(Qb, Kb, Vb, Yb);
  const unsigned short* wo_b;
  if (wo_in_prep) {
    wo_b = wob;
  } else {
    dequant_auto<<<dim3(8192), 256, 0, stream>>>(wo, x, wbuf);
    wo_b = wbuf;
  }
  gemm8_bt<<<dim3(16, 16), 512, 0, stream>>>(Yb, wo_b, out, DIMC, DIMC);
}

// Round 8
// 393.333 us; speedup vs baseline: 1.0905x; 1.0905x over previous
//
#include <hip/hip_runtime.h>
#include <stdint.h>
#include <math.h>

#define DIMC 2048
#define NHEADS 16
#define HDIM 128
#define TSEQ 2048
#define NTOK 4096   // B*T

using bf16x8 = __attribute__((ext_vector_type(8))) short;
using f32x4  = __attribute__((ext_vector_type(4))) float;

typedef __attribute__((address_space(1))) const void gas_void;
typedef __attribute__((address_space(3))) void las_void;

static __device__ __forceinline__ unsigned short f2b(float f) {
  union { float f; unsigned int u; } a; a.f = f;
  unsigned int u = a.u;
  u = (u + 0x7fffu + ((u >> 16) & 1u)) >> 16;   // RNE
  return (unsigned short)u;
}
static __device__ __forceinline__ float b2f(unsigned short s) {
  union { unsigned int u; float f; } a; a.u = ((unsigned int)s) << 16;
  return a.f;
}

// wave-uniform input dtype detect (bf16 vs fp32) from x's first 128 shorts.
static __device__ __forceinline__ int detect_inline(const void* __restrict__ x)
{
  const int lane = threadIdx.x & 63;
  const unsigned short u = ((const unsigned short*)x)[2 * lane];
  const int e = (u >> 7) & 0xFF;
  const unsigned long long m = __ballot((e >= 112) && (e <= 135));
  return (__popcll(m) >= 32) ? 1 : 0;
}

// ---------------- ternary dequant core (dtype-flag branched) --------------
// Threshold via multiply: wn>0.5 <=> a>0.5*scale (0.5*scale exact in FP) —
// no f64 divides. Verified R7: absmax unchanged.
static __device__ __forceinline__ void dequant_one(
    const void* __restrict__ w, unsigned short* __restrict__ o,
    int grp, int lane, int isbf16)
{
  float a, bq;
  if (isbf16) {
    const unsigned int pk =
        ((const unsigned int*)((const unsigned short*)w + (long)grp * 128))[lane];
    a  = b2f((unsigned short)(pk & 0xffffu));
    bq = b2f((unsigned short)(pk >> 16));
  } else {
    const float2 v = ((const float2*)((const float*)w + (long)grp * 128))[lane];
    a = v.x; bq = v.y;
  }
  double s = fabs((double)a) + fabs((double)bq);
  #pragma unroll
  for (int off = 1; off < 64; off <<= 1) s += __shfl_xor(s, off);
  double scale = s * (1.0 / 128.0);
  if (scale < 1e-8) scale = 1e-8;
  const float fs = (float)scale;
  const double hs = 0.5 * scale;
  const double da = (double)a, db = (double)bq;
  const float q0 = (da > hs) ? fs : ((da < -hs) ? -fs : 0.0f);
  const float q1 = (db > hs) ? fs : ((db < -hs) ? -fs : 0.0f);
  const unsigned int opk = (unsigned int)f2b(q0) | ((unsigned int)f2b(q1) << 16);
  ((unsigned int*)o)[(long)grp * 64 + lane] = opk;
}

// fused prep: y=0 cast x->bf16; y=1..3 dequant wq/wk/wv into row-stacked
// [6144][2048]; y=4 (only when ws has room) dequant wo into its own buffer.
__global__ void __launch_bounds__(256) prep(
    const void* __restrict__ x,
    const void* __restrict__ w0, const void* __restrict__ w1,
    const void* __restrict__ w2, const void* __restrict__ w3,
    unsigned short* __restrict__ xb, unsigned short* __restrict__ wqkv,
    unsigned short* __restrict__ wob)
{
  const int isbf16 = detect_inline(x);
  const int wave = threadIdx.x >> 6, lane = threadIdx.x & 63;
  const int y = blockIdx.y;
  if (y == 0) {
    const int i = (blockIdx.x * 256 + threadIdx.x) * 4;
    if (isbf16) {
      *(ushort4*)(xb + i) = *(const ushort4*)((const unsigned short*)x + i);
    } else {
      const float4 v = *(const float4*)((const float*)x + i);
      ushort4 u;
      u.x = f2b(v.x); u.y = f2b(v.y); u.z = f2b(v.z); u.w = f2b(v.w);
      *(ushort4*)(xb + i) = u;
    }
  } else if (y <= 3) {
    const void* w = (y == 1) ? w0 : (y == 2) ? w1 : w2;
    dequant_one(w, wqkv + (long)(y - 1) * DIMC * DIMC,
                blockIdx.x * 4 + wave, lane, isbf16);
  } else {
    dequant_one(w3, wob, blockIdx.x * 4 + wave, lane, isbf16);
  }
}

// fallback wo-dequant (inline flag) when ws can't host a separate wo buffer
__global__ void __launch_bounds__(256) dequant_auto(
    const void* __restrict__ w, const void* __restrict__ x,
    unsigned short* __restrict__ o)
{
  const int isbf16 = detect_inline(x);
  dequant_one(w, o, blockIdx.x * 4 + (threadIdx.x >> 6), threadIdx.x & 63,
              isbf16);
}

// ========== 256x128-tile 8-wave 2-phase-per-K GEMM, A 2-tiles-ahead =======
// R6 measured 3000 cyc/K-tile vs ~300 MFMA + ~500 LDS floor: the stall is
// EXPOSED STAGING LATENCY (1 block/CU, lockstep barriers, A(t+1) waited
// only ~1.5 phases after issue). Fix: triple-buffer A and stage A(t+2)
// (>=1 full tile in flight before its wait). LDS = 3x32K(A) + 2x16K(B)
// = 128 KB, still 1 block/CU (R1 ran 128 KB fine).
// Schedule per K-tile t:
//  ph1: 16 ds_reads (smA[t%3], smB[t&1]) | stage A(t+2)->smA[(t+2)%3]
//       | BAR | lgkm0 | 16 MFMA n01 | BAR
//  ph2: stage B(t+2)->smB[t&1] | 16 MFMA n23 | vmcnt(6) | BAR
// vmcnt ledger: steady ph2-end outstanding = {A(t+2):4, B(t+2):2} ->
// vmcnt(6) drains A(t+1),B(t+1) (issued >=1 tile earlier). t=NT-2 -> 0.
// Prologue issue ORDER A0,B0,A1,B1 so vmcnt(6) keeps exactly {A1,B1}.
// Overwrite safety: every buffer's readers passed their own lgkm0 before
// the barrier that precedes the overwriting stage (no latency assumptions).
static __device__ __forceinline__ void gemm8_core(
    const unsigned short* __restrict__ A, const unsigned short* __restrict__ Bm,
    int m0, int n0, int K, f32x4 (&acc)[4][4],
    unsigned short (*smA)[2][8192], unsigned short (*smB)[8192])
{
  const int tid = threadIdx.x;
  const int w = tid >> 6, lane = tid & 63;
  const int wr = w >> 1, wc = w & 1;
  const int c16 = lane & 15, q4 = lane >> 4;
  const int swz = (c16 * 32 + q4 * 8) ^ ((c16 & 8) ? 16 : 0);
  const int srow = lane >> 2;
  const int scol = ((lane & 3) * 8) ^ ((lane & 32) ? 16 : 0);
  const int rg0 = w >> 1, cg = w & 1;
  const int NT = K >> 6;

  #pragma unroll
  for (int i = 0; i < 4; i++)
    #pragma unroll
    for (int j = 0; j < 4; j++) acc[i][j] = (f32x4){0.f, 0.f, 0.f, 0.f};

  auto stage = [&](const unsigned short* __restrict__ G, int rowbase, int kt,
                   unsigned short* dst) {
    #pragma unroll
    for (int l = 0; l < 2; l++) {
      const unsigned short* s = G +
          (long)(rowbase + (rg0 + l * 4) * 16 + srow) * K + kt * 64 + cg * 32 + scol;
      __builtin_amdgcn_global_load_lds((gas_void*)s,
          (las_void*)(dst + (l * 8 + w) * 512), 16, 0, 0);
    }
  };

  // prologue — issue order matters for the vmcnt ledger: A0,B0,A1,B1
  stage(A,  m0,       0, smA[0][0]);
  stage(A,  m0 + 128, 0, smA[0][1]);
  stage(Bm, n0,       0, smB[0]);
  stage(A,  m0,       1, smA[1][0]);
  stage(A,  m0 + 128, 1, smA[1][1]);
  stage(Bm, n0,       1, smB[1]);
  asm volatile("s_waitcnt vmcnt(6)" ::: "memory");   // A0,B0 done; A1,B1 fly
  __builtin_amdgcn_s_barrier();

  bf16x8 af[4][2], b01[2][2], b23[2][2];
  const int ah = wr >> 1;               // which A 128-row half
  const int abase = (wr & 1) * 4096;    // 4 subtiles into that half
  const int bbase = wc * 4096;          // B cols wc*64

  int ai = 0, a2 = 2;                   // read buf (t%3), stage buf ((t+2)%3)
  for (int t = 0; t < NT; ++t) {
    const int bi = t & 1;

    // -------- phase 1 --------
    #pragma unroll
    for (int m = 0; m < 4; m++)
      #pragma unroll
      for (int kk = 0; kk < 2; kk++)
        af[m][kk] = *(const bf16x8*)&smA[ai][ah][abase + m * 1024 + kk * 512 + swz];
    #pragma unroll
    for (int n = 0; n < 2; n++)
      #pragma unroll
      for (int kk = 0; kk < 2; kk++) {
        b01[n][kk] = *(const bf16x8*)&smB[bi][bbase + n * 1024 + kk * 512 + swz];
        b23[n][kk] = *(const bf16x8*)&smB[bi][bbase + (2 + n) * 1024 + kk * 512 + swz];
      }
    if (t + 2 < NT) {
      stage(A, m0,       t + 2, smA[a2][0]);
      stage(A, m0 + 128, t + 2, smA[a2][1]);
    }
    __builtin_amdgcn_s_barrier();
    asm volatile("s_waitcnt lgkmcnt(0)" ::: "memory");
    __builtin_amdgcn_s_setprio(1);
    #pragma unroll
    for (int kk = 0; kk < 2; kk++)
      #pragma unroll
      for (int m = 0; m < 4; m++)
        #pragma unroll
        for (int n = 0; n < 2; n++)
          acc[m][n] = __builtin_amdgcn_mfma_f32_16x16x32_bf16(
              af[m][kk], b01[n][kk], acc[m][n], 0, 0, 0);
    __builtin_amdgcn_s_setprio(0);
    __builtin_amdgcn_s_barrier();

    // -------- phase 2 --------
    if (t + 2 < NT) stage(Bm, n0, t + 2, smB[bi]);   // (t+2)&1 == bi
    __builtin_amdgcn_s_setprio(1);
    #pragma unroll
    for (int kk = 0; kk < 2; kk++)
      #pragma unroll
      for (int m = 0; m < 4; m++)
        #pragma unroll
        for (int n = 0; n < 2; n++)
          acc[m][2 + n] = __builtin_amdgcn_mfma_f32_16x16x32_bf16(
              af[m][kk], b23[n][kk], acc[m][2 + n], 0, 0, 0);
    __builtin_amdgcn_s_setprio(0);
    if (t + 1 < NT) {
      if (t + 2 < NT) { asm volatile("s_waitcnt vmcnt(6)" ::: "memory"); }
      else            { asm volatile("s_waitcnt vmcnt(0)" ::: "memory"); }
      __builtin_amdgcn_s_barrier();
    }
    ai = (ai == 2) ? 0 : ai + 1;
    a2 = (a2 == 2) ? 0 : a2 + 1;
  }
}

// QKV: B row-stacked [6144][2048]; 128-col slab routed per output buffer.
// Grid (48,16) as in R6 (the R7 transpose is reverted with the rope fusion).
__global__ void __launch_bounds__(512, 2) gemm8_qkv(
    const unsigned short* __restrict__ A, const unsigned short* __restrict__ Bm,
    unsigned short* __restrict__ C0, unsigned short* __restrict__ C1,
    unsigned short* __restrict__ C2, int K)
{
  __shared__ unsigned short smA[3][2][8192];  // 96 KB
  __shared__ unsigned short smB[2][8192];     // 32 KB
  const int n0 = blockIdx.x * 128;            // 0..6143
  const int m0 = blockIdx.y * 256;
  f32x4 acc[4][4];
  gemm8_core(A, Bm, m0, n0, K, acc, smA, smB);

  unsigned short* Cb = (n0 < 2048) ? C0 : (n0 < 4096) ? C1 : C2;
  const int w = threadIdx.x >> 6, lane = threadIdx.x & 63;
  const int wr = w >> 1, wc = w & 1;
  const int c16 = lane & 15, q4 = lane >> 4;
  const int nloc = (n0 & 2047) + wc * 64;
  #pragma unroll
  for (int mt = 0; mt < 4; mt++) {
    const int m = m0 + wr * 64 + mt * 16 + q4 * 4;
    #pragma unroll
    for (int nt = 0; nt < 4; nt++) {
      const int n = nloc + nt * 16 + c16;
      #pragma unroll
      for (int r = 0; r < 4; r++)
        Cb[(long)(m + r) * DIMC + n] = f2b(acc[mt][nt][r]);
    }
  }
}

// wo projection: fp32 output, direct [4096][2048] (256 blocks = 1.0 round)
__global__ void __launch_bounds__(512, 2) gemm8_bt(
    const unsigned short* __restrict__ A, const unsigned short* __restrict__ Bm,
    float* __restrict__ C, int N, int K)
{
  __shared__ unsigned short smA[3][2][8192];  // 96 KB
  __shared__ unsigned short smB[2][8192];     // 32 KB
  const int n0 = blockIdx.x * 128;
  const int m0 = blockIdx.y * 256;
  f32x4 acc[4][4];
  gemm8_core(A, Bm, m0, n0, K, acc, smA, smB);

  const int w = threadIdx.x >> 6, lane = threadIdx.x & 63;
  const int wr = w >> 1, wc = w & 1;
  const int c16 = lane & 15, q4 = lane >> 4;
  #pragma unroll
  for (int mt = 0; mt < 4; mt++) {
    const int m = m0 + wr * 64 + mt * 16 + q4 * 4;
    #pragma unroll
    for (int nt = 0; nt < 4; nt++) {
      const int n = n0 + wc * 64 + nt * 16 + c16;
      #pragma unroll
      for (int r = 0; r < 4; r++)
        C[(long)(m + r) * N + n] = acc[mt][nt][r];
    }
  }
}

// ---------------- RoPE in-place on Q and K (bf16), 4 d/thread ------------
// Standalone (R6-proven). The R7 epilogue fusion exploded WRITE_SIZE 5x
// (sincosf scratch traffic under register pressure) — reverted.
__global__ void __launch_bounds__(256) rope_kernel(
    unsigned short* __restrict__ Q, unsigned short* __restrict__ Kb)
{
  const int idx = blockIdx.x * 256 + threadIdx.x;   // 0..1048575
  const int d4 = (idx & 15) * 4;                    // 0,4,..,60
  const int h = (idx >> 4) & (NHEADS - 1);
  const int row = idx >> 8;                         // 0..4095
  const int t = row & (TSEQ - 1);
  const long base = (long)row * DIMC + h * HDIM + d4;

  ushort4 q1 = *(ushort4*)(Q + base), q2 = *(ushort4*)(Q + base + 64);
  ushort4 k1 = *(ushort4*)(Kb + base), k2 = *(ushort4*)(Kb + base + 64);
  unsigned short* q1p = (unsigned short*)&q1;
  unsigned short* q2p = (unsigned short*)&q2;
  unsigned short* k1p = (unsigned short*)&k1;
  unsigned short* k2p = (unsigned short*)&k2;

  #pragma unroll
  for (int j = 0; j < 4; j++) {
    const int d = d4 + j;
    const float inv_freq = expf(-9.210340371976184f * (float)d * (1.0f / 64.0f));
    float sn, cs;
    sincosf((float)t * inv_freq, &sn, &cs);
    float x1 = b2f(q1p[j]), x2 = b2f(q2p[j]);
    q1p[j] = f2b(x1 * cs - x2 * sn);
    q2p[j] = f2b(x1 * sn + x2 * cs);
    x1 = b2f(k1p[j]); x2 = b2f(k2p[j]);
    k1p[j] = f2b(x1 * cs - x2 * sn);
    k2p[j] = f2b(x1 * sn + x2 * cs);
  }
  *(ushort4*)(Q + base) = q1;  *(ushort4*)(Q + base + 64) = q2;
  *(ushort4*)(Kb + base) = k1; *(ushort4*)(Kb + base + 64) = k2;
}

// ---------------- flash attention v3 (causal), bf16 MFMA ----------------
// EXACT round-0 version (best-measured state; R2/R3 variants regressed).
#define FA_M 16.0f
__global__ void __launch_bounds__(256) fattn(
    const unsigned short* __restrict__ Q,
    const unsigned short* __restrict__ K,
    const unsigned short* __restrict__ V,
    unsigned short* __restrict__ Y)
{
  __shared__ unsigned short SU[9216];       // 18432 B union (Ks | Ps)
  __shared__ unsigned short VT[128 * 72];   // 18432 B
  __shared__ float red[4][32];

  const int tid = threadIdx.x, wave = tid >> 6, lane = tid & 63;
  const int idx = blockIdx.x;               // 512 blocks
  const int qt = 15 - (idx >> 5);           // heaviest (qt=15) first
  const int bh = idx & 31;
  const int b = bh >> 4, h = bh & 15;
  const int qbase = qt * 128;
  const int qw = wave * 32;
  const int c = lane & 15, g = lane >> 4;
  const long tokbase = (long)b * TSEQ;
  const int col0 = h * HDIM;

  bf16x8 qf[2][4];
  #pragma unroll
  for (int qq = 0; qq < 2; qq++) {
    const unsigned short* qp =
        Q + (tokbase + qbase + qw + qq * 16 + c) * DIMC + col0 + g * 8;
    #pragma unroll
    for (int kc = 0; kc < 4; kc++) qf[qq][kc] = *(const bf16x8*)(qp + kc * 32);
  }

  f32x4 od[8][2];
  #pragma unroll
  for (int dt = 0; dt < 8; dt++)
    #pragma unroll
    for (int qq = 0; qq < 2; qq++)
      od[dt][qq] = (f32x4){0.f, 0.f, 0.f, 0.f};
  float lpart[2][4];
  #pragma unroll
  for (int qq = 0; qq < 2; qq++)
    #pragma unroll
    for (int r = 0; r < 4; r++) lpart[qq][r] = 0.0f;

  const int ksr = tid >> 2, ksc = (tid & 3) * 32;
  const int vk0 = (tid & 31) * 2, vd0 = (tid >> 5) * 16;

  const float SC = 0.088388347648318447f;  // 1/sqrt(128)
  const int nkt = 2 * qt + 2;

  // prefetch registers (K row chunk: 4x float4; V: 2 keys x 16 d)
  float4 kr0, kr1, kr2, kr3;
  bf16x8 va0, va1, vb0, vb1;
  {
    const unsigned short* src = K + (tokbase + ksr) * DIMC + col0 + ksc;
    kr0 = ((const float4*)src)[0]; kr1 = ((const float4*)src)[1];
    kr2 = ((const float4*)src)[2]; kr3 = ((const float4*)src)[3];
    const unsigned short* s0 = V + (tokbase + vk0) * DIMC + col0 + vd0;
    const unsigned short* s1 = s0 + DIMC;
    va0 = *(const bf16x8*)(s0); va1 = *(const bf16x8*)(s0 + 8);
    vb0 = *(const bf16x8*)(s1); vb1 = *(const bf16x8*)(s1 + 8);
  }

  for (int kt = 0; kt < nkt; kt++) {
    const int kb = kt * 64;
    __syncthreads();   // A: prev-iter readers done with SU/VT
    {
      float4* dst = (float4*)&SU[ksr * 136 + ksc];
      dst[0] = kr0; dst[1] = kr1; dst[2] = kr2; dst[3] = kr3;
    }
    {
      #pragma unroll
      for (int dd = 0; dd < 8; dd++) {
        const unsigned int p0 =
            (unsigned int)(unsigned short)va0[dd] |
            ((unsigned int)(unsigned short)vb0[dd] << 16);
        *(unsigned int*)&VT[(vd0 + dd) * 72 + vk0] = p0;
      }
      #pragma unroll
      for (int dd = 0; dd < 8; dd++) {
        const unsigned int p1 =
            (unsigned int)(unsigned short)va1[dd] |
            ((unsigned int)(unsigned short)vb1[dd] << 16);
        *(unsigned int*)&VT[(vd0 + 8 + dd) * 72 + vk0] = p1;
      }
    }
    __syncthreads();   // B: staging visible

    if (kt + 1 < nkt) {   // issue next tile's loads; consumed at next barrier A
      const int kb2 = kb + 64;
      const unsigned short* src = K + (tokbase + kb2 + ksr) * DIMC + col0 + ksc;
      kr0 = ((const float4*)src)[0]; kr1 = ((const float4*)src)[1];
      kr2 = ((const float4*)src)[2]; kr3 = ((const float4*)src)[3];
      const unsigned short* s0 = V + (tokbase + kb2 + vk0) * DIMC + col0 + vd0;
      const unsigned short* s1 = s0 + DIMC;
      va0 = *(const bf16x8*)(s0); va1 = *(const bf16x8*)(s0 + 8);
      vb0 = *(const bf16x8*)(s1); vb1 = *(const bf16x8*)(s1 + 8);
    }

    f32x4 sacc[2][4];
    #pragma unroll
    for (int qq = 0; qq < 2; qq++)
      #pragma unroll
      for (int nt = 0; nt < 4; nt++) sacc[qq][nt] = (f32x4){0.f, 0.f, 0.f, 0.f};
    #pragma unroll
    for (int kc = 0; kc < 4; kc++) {
      bf16x8 bk[4];
      #pragma unroll
      for (int nt = 0; nt < 4; nt++)
        bk[nt] = *(const bf16x8*)&SU[(nt * 16 + c) * 136 + kc * 32 + g * 8];
      #pragma unroll
      for (int qq = 0; qq < 2; qq++)
        #pragma unroll
        for (int nt = 0; nt < 4; nt++)
          sacc[qq][nt] = __builtin_amdgcn_mfma_f32_16x16x32_bf16(
              qf[qq][kc], bk[nt], sacc[qq][nt], 0, 0, 0);
    }
    __syncthreads();   // C: Ks reads done before Ps overwrites SU

    #pragma unroll
    for (int qq = 0; qq < 2; qq++)
      #pragma unroll
      for (int r = 0; r < 4; r++) {
        const int qg = qbase + qw + qq * 16 + g * 4 + r;
        #pragma unroll
        for (int nt = 0; nt < 4; nt++) {
          const int kg = kb + nt * 16 + c;
          const float sv = sacc[qq][nt][r] * SC - FA_M;
          const float p = (kg > qg) ? 0.0f : __expf(sv);
          lpart[qq][r] += p;
          SU[(wave * 32 + qq * 16 + g * 4 + r) * 72 + nt * 16 + c] = f2b(p);
        }
      }

    #pragma unroll
    for (int kc = 0; kc < 2; kc++) {
      bf16x8 pb[2];
      #pragma unroll
      for (int qq = 0; qq < 2; qq++)
        pb[qq] = *(const bf16x8*)&SU[(wave * 32 + qq * 16 + c) * 72 + kc * 32 + g * 8];
      #pragma unroll
      for (int dt = 0; dt < 8; dt++) {
        bf16x8 va = *(const bf16x8*)&VT[(dt * 16 + c) * 72 + kc * 32 + g * 8];
        #pragma unroll
        for (int qq = 0; qq < 2; qq++)
          od[dt][qq] = __builtin_amdgcn_mfma_f32_16x16x32_bf16(
              va, pb[qq], od[dt][qq], 0, 0, 0);
      }
    }
  }

  #pragma unroll
  for (int qq = 0; qq < 2; qq++)
    #pragma unroll
    for (int r = 0; r < 4; r++) {
      float l = lpart[qq][r];
      #pragma unroll
      for (int off = 1; off < 16; off <<= 1) l += __shfl_xor(l, off);
      lpart[qq][r] = l;
    }
  __syncthreads();
  if (c == 0) {
    #pragma unroll
    for (int qq = 0; qq < 2; qq++)
      #pragma unroll
      for (int r = 0; r < 4; r++)
        red[wave][qq * 16 + g * 4 + r] = 1.0f / lpart[qq][r];
  }
  __syncthreads();
  #pragma unroll
  for (int qq = 0; qq < 2; qq++) {
    const float linv = red[wave][qq * 16 + c];
    unsigned short* yp =
        Y + (tokbase + qbase + qw + qq * 16 + c) * DIMC + col0;
    #pragma unroll
    for (int dt = 0; dt < 8; dt++)
      #pragma unroll
      for (int r = 0; r < 4; r++)
        yp[dt * 16 + g * 4 + r] = f2b(od[dt][qq][r] * linv);
  }
}

extern "C" void kernel_launch(void* const* d_in, const int* in_sizes, int n_in,
                              void* d_out, int out_size, void* d_ws, size_t ws_size,
                              hipStream_t stream)
{
  const void* x  = d_in[0];
  const void* wq = d_in[1];
  const void* wk = d_in[2];
  const void* wv = d_in[3];
  const void* wo = d_in[4];
  float* out = (float*)d_out;

  char* ws = (char*)d_ws;
  const size_t MB = 1024 * 1024;
  unsigned short* wbuf = (unsigned short*)(ws + 0 * MB);   // 24 MB (QKV stacked)
  unsigned short* xb   = (unsigned short*)(ws + 24 * MB);  // 16 MB
  unsigned short* Qb   = (unsigned short*)(ws + 40 * MB);  // 16 MB
  unsigned short* Kb   = (unsigned short*)(ws + 56 * MB);  // 16 MB
  unsigned short* Vb   = (unsigned short*)(ws + 72 * MB);  // 16 MB
  unsigned short* wob  = (unsigned short*)(ws + 88 * MB);  // 8 MB (if room)
  unsigned short* Yb   = xb;   // x dead after QKV projection; alias.

  const int wo_in_prep = (ws_size >= 97 * MB) ? 1 : 0;

  prep<<<dim3(8192, wo_in_prep ? 5 : 4), 256, 0, stream>>>(
      x, wq, wk, wv, wo, xb, wbuf, wob);
  gemm8_qkv<<<dim3(48, 16), 512, 0, stream>>>(xb, wbuf, Qb, Kb, Vb, DIMC);
  rope_kernel<<<dim3(4096), 256, 0, stream>>>(Qb, Kb);
  fattn<<<dim3(512), 256, 0, stream>>>(Qb, Kb, Vb, Yb);
  const unsigned short* wo_b;
  if (wo_in_prep) {
    wo_b = wob;
  } else {
    dequant_auto<<<dim3(8192), 256, 0, stream>>>(wo, x, wbuf);
    wo_b = wbuf;
  }
  gemm8_bt<<<dim3(16, 16), 512, 0, stream>>>(Yb, wo_b, out, DIMC, DIMC);
}

// Round 9
// 386.395 us; speedup vs baseline: 1.1101x; 1.0180x over previous
//
#include <hip/hip_runtime.h>
#include <stdint.h>
#include <math.h>

#define DIMC 2048
#define NHEADS 16
#define HDIM 128
#define TSEQ 2048
#define NTOK 4096   // B*T

using bf16x8 = __attribute__((ext_vector_type(8))) short;
using f32x4  = __attribute__((ext_vector_type(4))) float;

typedef __attribute__((address_space(1))) const void gas_void;
typedef __attribute__((address_space(3))) void las_void;

static __device__ __forceinline__ unsigned short f2b(float f) {
  union { float f; unsigned int u; } a; a.f = f;
  unsigned int u = a.u;
  u = (u + 0x7fffu + ((u >> 16) & 1u)) >> 16;   // RNE
  return (unsigned short)u;
}
static __device__ __forceinline__ float b2f(unsigned short s) {
  union { unsigned int u; float f; } a; a.u = ((unsigned int)s) << 16;
  return a.f;
}

// wave-uniform input dtype detect (bf16 vs fp32) from x's first 128 shorts.
static __device__ __forceinline__ int detect_inline(const void* __restrict__ x)
{
  const int lane = threadIdx.x & 63;
  const unsigned short u = ((const unsigned short*)x)[2 * lane];
  const int e = (u >> 7) & 0xFF;
  const unsigned long long m = __ballot((e >= 112) && (e <= 135));
  return (__popcll(m) >= 32) ? 1 : 0;
}

// ---------------- ternary dequant core (dtype-flag branched) --------------
// Threshold via multiply (R7-verified, absmax unchanged): no f64 divides.
static __device__ __forceinline__ void dequant_one(
    const void* __restrict__ w, unsigned short* __restrict__ o,
    int grp, int lane, int isbf16)
{
  float a, bq;
  if (isbf16) {
    const unsigned int pk =
        ((const unsigned int*)((const unsigned short*)w + (long)grp * 128))[lane];
    a  = b2f((unsigned short)(pk & 0xffffu));
    bq = b2f((unsigned short)(pk >> 16));
  } else {
    const float2 v = ((const float2*)((const float*)w + (long)grp * 128))[lane];
    a = v.x; bq = v.y;
  }
  double s = fabs((double)a) + fabs((double)bq);
  #pragma unroll
  for (int off = 1; off < 64; off <<= 1) s += __shfl_xor(s, off);
  double scale = s * (1.0 / 128.0);
  if (scale < 1e-8) scale = 1e-8;
  const float fs = (float)scale;
  const double hs = 0.5 * scale;
  const double da = (double)a, db = (double)bq;
  const float q0 = (da > hs) ? fs : ((da < -hs) ? -fs : 0.0f);
  const float q1 = (db > hs) ? fs : ((db < -hs) ? -fs : 0.0f);
  const unsigned int opk = (unsigned int)f2b(q0) | ((unsigned int)f2b(q1) << 16);
  ((unsigned int*)o)[(long)grp * 64 + lane] = opk;
}

// fused prep, FATTER blocks (2048 x-blocks, x4 inner loop — cuts per-block
// dispatch overhead on 3KB/block work): y=0 cast x->bf16; y=1..3 dequant
// wq/wk/wv row-stacked; y=4 (when ws has room) dequant wo.
__global__ void __launch_bounds__(256) prep(
    const void* __restrict__ x,
    const void* __restrict__ w0, const void* __restrict__ w1,
    const void* __restrict__ w2, const void* __restrict__ w3,
    unsigned short* __restrict__ xb, unsigned short* __restrict__ wqkv,
    unsigned short* __restrict__ wob)
{
  const int isbf16 = detect_inline(x);
  const int wave = threadIdx.x >> 6, lane = threadIdx.x & 63;
  const int y = blockIdx.y;
  if (y == 0) {
    #pragma unroll
    for (int it = 0; it < 4; it++) {
      const int i = ((blockIdx.x * 4 + it) * 256 + threadIdx.x) * 4;
      if (isbf16) {
        *(ushort4*)(xb + i) = *(const ushort4*)((const unsigned short*)x + i);
      } else {
        const float4 v = *(const float4*)((const float*)x + i);
        ushort4 u;
        u.x = f2b(v.x); u.y = f2b(v.y); u.z = f2b(v.z); u.w = f2b(v.w);
        *(ushort4*)(xb + i) = u;
      }
    }
  } else if (y <= 3) {
    const void* w = (y == 1) ? w0 : (y == 2) ? w1 : w2;
    unsigned short* oo = wqkv + (long)(y - 1) * DIMC * DIMC;
    #pragma unroll
    for (int it = 0; it < 4; it++)
      dequant_one(w, oo, (blockIdx.x * 4 + it) * 4 + wave, lane, isbf16);
  } else {
    #pragma unroll
    for (int it = 0; it < 4; it++)
      dequant_one(w3, wob, (blockIdx.x * 4 + it) * 4 + wave, lane, isbf16);
  }
}

// fallback wo-dequant (inline flag) when ws can't host a separate wo buffer
__global__ void __launch_bounds__(256) dequant_auto(
    const void* __restrict__ w, const void* __restrict__ x,
    unsigned short* __restrict__ o)
{
  const int isbf16 = detect_inline(x);
  dequant_one(w, o, blockIdx.x * 4 + (threadIdx.x >> 6), threadIdx.x & 63,
              isbf16);
}

// ========== 256x128-tile core (R6/R8-proven, kept for wo GEMM) ============
static __device__ __forceinline__ void gemm8_core(
    const unsigned short* __restrict__ A, const unsigned short* __restrict__ Bm,
    int m0, int n0, int K, f32x4 (&acc)[4][4],
    unsigned short (*smA)[2][8192], unsigned short (*smB)[8192])
{
  const int tid = threadIdx.x;
  const int w = tid >> 6, lane = tid & 63;
  const int wr = w >> 1, wc = w & 1;
  const int c16 = lane & 15, q4 = lane >> 4;
  const int swz = (c16 * 32 + q4 * 8) ^ ((c16 & 8) ? 16 : 0);
  const int srow = lane >> 2;
  const int scol = ((lane & 3) * 8) ^ ((lane & 32) ? 16 : 0);
  const int rg0 = w >> 1, cg = w & 1;
  const int NT = K >> 6;

  #pragma unroll
  for (int i = 0; i < 4; i++)
    #pragma unroll
    for (int j = 0; j < 4; j++) acc[i][j] = (f32x4){0.f, 0.f, 0.f, 0.f};

  auto stage = [&](const unsigned short* __restrict__ G, int rowbase, int kt,
                   unsigned short* dst) {
    #pragma unroll
    for (int l = 0; l < 2; l++) {
      const unsigned short* s = G +
          (long)(rowbase + (rg0 + l * 4) * 16 + srow) * K + kt * 64 + cg * 32 + scol;
      __builtin_amdgcn_global_load_lds((gas_void*)s,
          (las_void*)(dst + (l * 8 + w) * 512), 16, 0, 0);
    }
  };

  stage(A,  m0,       0, smA[0][0]);
  stage(A,  m0 + 128, 0, smA[0][1]);
  stage(Bm, n0,       0, smB[0]);
  stage(A,  m0,       1, smA[1][0]);
  stage(A,  m0 + 128, 1, smA[1][1]);
  stage(Bm, n0,       1, smB[1]);
  asm volatile("s_waitcnt vmcnt(6)" ::: "memory");
  __builtin_amdgcn_s_barrier();

  bf16x8 af[4][2], b01[2][2], b23[2][2];
  const int ah = wr >> 1;
  const int abase = (wr & 1) * 4096;
  const int bbase = wc * 4096;

  int ai = 0, a2 = 2;
  for (int t = 0; t < NT; ++t) {
    const int bi = t & 1;

    #pragma unroll
    for (int m = 0; m < 4; m++)
      #pragma unroll
      for (int kk = 0; kk < 2; kk++)
        af[m][kk] = *(const bf16x8*)&smA[ai][ah][abase + m * 1024 + kk * 512 + swz];
    #pragma unroll
    for (int n = 0; n < 2; n++)
      #pragma unroll
      for (int kk = 0; kk < 2; kk++) {
        b01[n][kk] = *(const bf16x8*)&smB[bi][bbase + n * 1024 + kk * 512 + swz];
        b23[n][kk] = *(const bf16x8*)&smB[bi][bbase + (2 + n) * 1024 + kk * 512 + swz];
      }
    if (t + 2 < NT) {
      stage(A, m0,       t + 2, smA[a2][0]);
      stage(A, m0 + 128, t + 2, smA[a2][1]);
    }
    __builtin_amdgcn_s_barrier();
    asm volatile("s_waitcnt lgkmcnt(0)" ::: "memory");
    __builtin_amdgcn_s_setprio(1);
    #pragma unroll
    for (int kk = 0; kk < 2; kk++)
      #pragma unroll
      for (int m = 0; m < 4; m++)
        #pragma unroll
        for (int n = 0; n < 2; n++)
          acc[m][n] = __builtin_amdgcn_mfma_f32_16x16x32_bf16(
              af[m][kk], b01[n][kk], acc[m][n], 0, 0, 0);
    __builtin_amdgcn_s_setprio(0);
    __builtin_amdgcn_s_barrier();

    if (t + 2 < NT) stage(Bm, n0, t + 2, smB[bi]);
    __builtin_amdgcn_s_setprio(1);
    #pragma unroll
    for (int kk = 0; kk < 2; kk++)
      #pragma unroll
      for (int m = 0; m < 4; m++)
        #pragma unroll
        for (int n = 0; n < 2; n++)
          acc[m][2 + n] = __builtin_amdgcn_mfma_f32_16x16x32_bf16(
              af[m][kk], b23[n][kk], acc[m][2 + n], 0, 0, 0);
    __builtin_amdgcn_s_setprio(0);
    if (t + 1 < NT) {
      if (t + 2 < NT) { asm volatile("s_waitcnt vmcnt(6)" ::: "memory"); }
      else            { asm volatile("s_waitcnt vmcnt(0)" ::: "memory"); }
      __builtin_amdgcn_s_barrier();
    }
    ai = (ai == 2) ? 0 : ai + 1;
    a2 = (a2 == 2) ? 0 : a2 + 1;
  }
}

// wo projection: fp32 output (256 blocks = 1.0 round) — R8-proven.
__global__ void __launch_bounds__(512, 2) gemm8_bt(
    const unsigned short* __restrict__ A, const unsigned short* __restrict__ Bm,
    float* __restrict__ C, int N, int K)
{
  __shared__ unsigned short smA[3][2][8192];  // 96 KB
  __shared__ unsigned short smB[2][8192];     // 32 KB
  const int n0 = blockIdx.x * 128;
  const int m0 = blockIdx.y * 256;
  f32x4 acc[4][4];
  gemm8_core(A, Bm, m0, n0, K, acc, smA, smB);

  const int w = threadIdx.x >> 6, lane = threadIdx.x & 63;
  const int wr = w >> 1, wc = w & 1;
  const int c16 = lane & 15, q4 = lane >> 4;
  #pragma unroll
  for (int mt = 0; mt < 4; mt++) {
    const int m = m0 + wr * 64 + mt * 16 + q4 * 4;
    #pragma unroll
    for (int nt = 0; nt < 4; nt++) {
      const int n = n0 + wc * 64 + nt * 16 + c16;
      #pragma unroll
      for (int r = 0; r < 4; r++)
        C[(long)(m + r) * N + n] = acc[mt][nt][r];
    }
  }
}

// ========== 256x256-tile QKV GEMM (R1 schedule, refcheck-proven) ==========
// R6/R8 256x128 is LDS-BW-bound (~2100/3000 cyc per tile in the LDS pipe);
// acc[8][4] (128x64/wave) cuts LDS reads/FLOP 25% and doubles MFMA/phase.
// Grid 16x24 = 384 blocks (1.5 rounds accepted; R1 per-round 1067 TF).
// Deltas vs R1: __launch_bounds__(512,1) (occupancy LDS-pinned at 1
// block/CU anyway — frees regalloc) + compile-time K.
__global__ void __launch_bounds__(512, 1) gemm256_qkv(
    const unsigned short* __restrict__ A, const unsigned short* __restrict__ Bm,
    unsigned short* __restrict__ C0, unsigned short* __restrict__ C1,
    unsigned short* __restrict__ C2)
{
  __shared__ unsigned short sm[2][2][2][8192];   // 131072 B
  const int K = DIMC, NT = K >> 6;

  const int tid = threadIdx.x;
  const int w = tid >> 6, lane = tid & 63;
  const int wr = w >> 2, wc = w & 3;
  const int wh = wc >> 1, wb = (wc & 1) * 4;
  const int c16 = lane & 15, q4 = lane >> 4;
  const int swz = (c16 * 32 + q4 * 8) ^ ((c16 & 8) ? 16 : 0);
  const int srow = lane >> 2;
  const int scol = ((lane & 3) * 8) ^ ((lane & 32) ? 16 : 0);
  const int rg0 = w >> 1, cg = w & 1;

  const int m0 = blockIdx.x * 256;   // x = m fastest: round 1 = 16x16 square
  const int n0 = blockIdx.y * 256;

  f32x4 acc[8][4];
  #pragma unroll
  for (int i = 0; i < 8; i++)
    #pragma unroll
    for (int j = 0; j < 4; j++) acc[i][j] = (f32x4){0.f, 0.f, 0.f, 0.f};

  auto stage = [&](const unsigned short* __restrict__ G, int rowbase, int kt,
                   unsigned short* dst) {
    #pragma unroll
    for (int l = 0; l < 2; l++) {
      const unsigned short* s = G +
          (long)(rowbase + (rg0 + l * 4) * 16 + srow) * K + kt * 64 + cg * 32 + scol;
      __builtin_amdgcn_global_load_lds((gas_void*)s,
          (las_void*)(dst + (l * 8 + w) * 512), 16, 0, 0);
    }
  };

  stage(A,  m0,       0, &sm[0][0][0][0]);
  stage(A,  m0 + 128, 0, &sm[0][0][1][0]);
  stage(Bm, n0,       0, &sm[0][1][0][0]);
  stage(Bm, n0 + 128, 0, &sm[0][1][1][0]);
  stage(Bm, n0,       1, &sm[1][1][0][0]);
  stage(Bm, n0 + 128, 1, &sm[1][1][1][0]);
  asm volatile("s_waitcnt vmcnt(4)" ::: "memory");
  __builtin_amdgcn_s_barrier();

  bf16x8 af[4][2], b01[2][2], b23[2][2];

  for (int t = 0; t < NT; ++t) {
    const int cur = t & 1, nxt = cur ^ 1;

    // -------- phase 1 --------
    #pragma unroll
    for (int m = 0; m < 4; m++)
      #pragma unroll
      for (int kk = 0; kk < 2; kk++)
        af[m][kk] = *(const bf16x8*)&sm[cur][0][wr][m * 1024 + kk * 512 + swz];
    #pragma unroll
    for (int n = 0; n < 2; n++)
      #pragma unroll
      for (int kk = 0; kk < 2; kk++)
        b01[n][kk] = *(const bf16x8*)&sm[cur][1][wh][(wb + n) * 1024 + kk * 512 + swz];
    if (t + 1 < NT) stage(A, m0, t + 1, &sm[nxt][0][0][0]);
    __builtin_amdgcn_s_barrier();
    asm volatile("s_waitcnt lgkmcnt(0)" ::: "memory");
    __builtin_amdgcn_s_setprio(1);
    #pragma unroll
    for (int kk = 0; kk < 2; kk++)
      #pragma unroll
      for (int m = 0; m < 4; m++)
        #pragma unroll
        for (int n = 0; n < 2; n++)
          acc[m][n] = __builtin_amdgcn_mfma_f32_16x16x32_bf16(
              af[m][kk], b01[n][kk], acc[m][n], 0, 0, 0);
    __builtin_amdgcn_s_setprio(0);
    __builtin_amdgcn_s_barrier();

    // -------- phase 2 --------
    #pragma unroll
    for (int n = 0; n < 2; n++)
      #pragma unroll
      for (int kk = 0; kk < 2; kk++)
        b23[n][kk] = *(const bf16x8*)&sm[cur][1][wh][(wb + 2 + n) * 1024 + kk * 512 + swz];
    if (t + 1 < NT) stage(A, m0 + 128, t + 1, &sm[nxt][0][1][0]);
    __builtin_amdgcn_s_barrier();
    asm volatile("s_waitcnt lgkmcnt(0)" ::: "memory");
    __builtin_amdgcn_s_setprio(1);
    #pragma unroll
    for (int kk = 0; kk < 2; kk++)
      #pragma unroll
      for (int m = 0; m < 4; m++)
        #pragma unroll
        for (int n = 0; n < 2; n++)
          acc[m][2 + n] = __builtin_amdgcn_mfma_f32_16x16x32_bf16(
              af[m][kk], b23[n][kk], acc[m][2 + n], 0, 0, 0);
    __builtin_amdgcn_s_setprio(0);
    __builtin_amdgcn_s_barrier();

    // -------- phase 3 --------
    #pragma unroll
    for (int m = 0; m < 4; m++)
      #pragma unroll
      for (int kk = 0; kk < 2; kk++)
        af[m][kk] = *(const bf16x8*)&sm[cur][0][wr][(4 + m) * 1024 + kk * 512 + swz];
    if (t + 2 < NT) stage(Bm, n0, t + 2, &sm[cur][1][0][0]);
    __builtin_amdgcn_s_barrier();
    asm volatile("s_waitcnt lgkmcnt(0)" ::: "memory");
    __builtin_amdgcn_s_setprio(1);
    #pragma unroll
    for (int kk = 0; kk < 2; kk++)
      #pragma unroll
      for (int m = 0; m < 4; m++)
        #pragma unroll
        for (int n = 0; n < 2; n++)
          acc[4 + m][2 + n] = __builtin_amdgcn_mfma_f32_16x16x32_bf16(
              af[m][kk], b23[n][kk], acc[4 + m][2 + n], 0, 0, 0);
    __builtin_amdgcn_s_setprio(0);
    __builtin_amdgcn_s_barrier();

    // -------- phase 4 --------
    if (t + 2 < NT) stage(Bm, n0 + 128, t + 2, &sm[cur][1][1][0]);
    __builtin_amdgcn_s_barrier();
    __builtin_amdgcn_s_setprio(1);
    #pragma unroll
    for (int kk = 0; kk < 2; kk++)
      #pragma unroll
      for (int m = 0; m < 4; m++)
        #pragma unroll
        for (int n = 0; n < 2; n++)
          acc[4 + m][n] = __builtin_amdgcn_mfma_f32_16x16x32_bf16(
              af[m][kk], b01[n][kk], acc[4 + m][n], 0, 0, 0);
    __builtin_amdgcn_s_setprio(0);
    if (t + 2 < NT) { asm volatile("s_waitcnt vmcnt(4)" ::: "memory"); }
    else            { asm volatile("s_waitcnt vmcnt(0)" ::: "memory"); }
    __builtin_amdgcn_s_barrier();
  }

  unsigned short* Cb = (n0 < 2048) ? C0 : (n0 < 4096) ? C1 : C2;
  const int nloc = (n0 & 2047) + wc * 64;
  #pragma unroll
  for (int mt = 0; mt < 8; mt++) {
    const int m = m0 + wr * 128 + mt * 16 + q4 * 4;
    #pragma unroll
    for (int nt = 0; nt < 4; nt++) {
      const int n = nloc + nt * 16 + c16;
      #pragma unroll
      for (int r = 0; r < 4; r++)
        Cb[(long)(m + r) * DIMC + n] = f2b(acc[mt][nt][r]);
    }
  }
}

// ---------------- RoPE in-place on Q and K (bf16), 4 d/thread ------------
__global__ void __launch_bounds__(256) rope_kernel(
    unsigned short* __restrict__ Q, unsigned short* __restrict__ Kb)
{
  const int idx = blockIdx.x * 256 + threadIdx.x;   // 0..1048575
  const int d4 = (idx & 15) * 4;
  const int h = (idx >> 4) & (NHEADS - 1);
  const int row = idx >> 8;
  const int t = row & (TSEQ - 1);
  const long base = (long)row * DIMC + h * HDIM + d4;

  ushort4 q1 = *(ushort4*)(Q + base), q2 = *(ushort4*)(Q + base + 64);
  ushort4 k1 = *(ushort4*)(Kb + base), k2 = *(ushort4*)(Kb + base + 64);
  unsigned short* q1p = (unsigned short*)&q1;
  unsigned short* q2p = (unsigned short*)&q2;
  unsigned short* k1p = (unsigned short*)&k1;
  unsigned short* k2p = (unsigned short*)&k2;

  #pragma unroll
  for (int j = 0; j < 4; j++) {
    const int d = d4 + j;
    const float inv_freq = expf(-9.210340371976184f * (float)d * (1.0f / 64.0f));
    float sn, cs;
    sincosf((float)t * inv_freq, &sn, &cs);
    float x1 = b2f(q1p[j]), x2 = b2f(q2p[j]);
    q1p[j] = f2b(x1 * cs - x2 * sn);
    q2p[j] = f2b(x1 * sn + x2 * cs);
    x1 = b2f(k1p[j]); x2 = b2f(k2p[j]);
    k1p[j] = f2b(x1 * cs - x2 * sn);
    k2p[j] = f2b(x1 * sn + x2 * cs);
  }
  *(ushort4*)(Q + base) = q1;  *(ushort4*)(Q + base + 64) = q2;
  *(ushort4*)(Kb + base) = k1; *(ushort4*)(Kb + base + 64) = k2;
}

// ---------------- flash attention v3 (causal), bf16 MFMA ----------------
// EXACT round-0 version (best-measured state).
#define FA_M 16.0f
__global__ void __launch_bounds__(256) fattn(
    const unsigned short* __restrict__ Q,
    const unsigned short* __restrict__ K,
    const unsigned short* __restrict__ V,
    unsigned short* __restrict__ Y)
{
  __shared__ unsigned short SU[9216];       // 18432 B union (Ks | Ps)
  __shared__ unsigned short VT[128 * 72];   // 18432 B
  __shared__ float red[4][32];

  const int tid = threadIdx.x, wave = tid >> 6, lane = tid & 63;
  const int idx = blockIdx.x;               // 512 blocks
  const int qt = 15 - (idx >> 5);           // heaviest (qt=15) first
  const int bh = idx & 31;
  const int b = bh >> 4, h = bh & 15;
  const int qbase = qt * 128;
  const int qw = wave * 32;
  const int c = lane & 15, g = lane >> 4;
  const long tokbase = (long)b * TSEQ;
  const int col0 = h * HDIM;

  bf16x8 qf[2][4];
  #pragma unroll
  for (int qq = 0; qq < 2; qq++) {
    const unsigned short* qp =
        Q + (tokbase + qbase + qw + qq * 16 + c) * DIMC + col0 + g * 8;
    #pragma unroll
    for (int kc = 0; kc < 4; kc++) qf[qq][kc] = *(const bf16x8*)(qp + kc * 32);
  }

  f32x4 od[8][2];
  #pragma unroll
  for (int dt = 0; dt < 8; dt++)
    #pragma unroll
    for (int qq = 0; qq < 2; qq++)
      od[dt][qq] = (f32x4){0.f, 0.f, 0.f, 0.f};
  float lpart[2][4];
  #pragma unroll
  for (int qq = 0; qq < 2; qq++)
    #pragma unroll
    for (int r = 0; r < 4; r++) lpart[qq][r] = 0.0f;

  const int ksr = tid >> 2, ksc = (tid & 3) * 32;
  const int vk0 = (tid & 31) * 2, vd0 = (tid >> 5) * 16;

  const float SC = 0.088388347648318447f;  // 1/sqrt(128)
  const int nkt = 2 * qt + 2;

  float4 kr0, kr1, kr2, kr3;
  bf16x8 va0, va1, vb0, vb1;
  {
    const unsigned short* src = K + (tokbase + ksr) * DIMC + col0 + ksc;
    kr0 = ((const float4*)src)[0]; kr1 = ((const float4*)src)[1];
    kr2 = ((const float4*)src)[2]; kr3 = ((const float4*)src)[3];
    const unsigned short* s0 = V + (tokbase + vk0) * DIMC + col0 + vd0;
    const unsigned short* s1 = s0 + DIMC;
    va0 = *(const bf16x8*)(s0); va1 = *(const bf16x8*)(s0 + 8);
    vb0 = *(const bf16x8*)(s1); vb1 = *(const bf16x8*)(s1 + 8);
  }

  for (int kt = 0; kt < nkt; kt++) {
    const int kb = kt * 64;
    __syncthreads();   // A: prev-iter readers done with SU/VT
    {
      float4* dst = (float4*)&SU[ksr * 136 + ksc];
      dst[0] = kr0; dst[1] = kr1; dst[2] = kr2; dst[3] = kr3;
    }
    {
      #pragma unroll
      for (int dd = 0; dd < 8; dd++) {
        const unsigned int p0 =
            (unsigned int)(unsigned short)va0[dd] |
            ((unsigned int)(unsigned short)vb0[dd] << 16);
        *(unsigned int*)&VT[(vd0 + dd) * 72 + vk0] = p0;
      }
      #pragma unroll
      for (int dd = 0; dd < 8; dd++) {
        const unsigned int p1 =
            (unsigned int)(unsigned short)va1[dd] |
            ((unsigned int)(unsigned short)vb1[dd] << 16);
        *(unsigned int*)&VT[(vd0 + 8 + dd) * 72 + vk0] = p1;
      }
    }
    __syncthreads();   // B: staging visible

    if (kt + 1 < nkt) {
      const int kb2 = kb + 64;
      const unsigned short* src = K + (tokbase + kb2 + ksr) * DIMC + col0 + ksc;
      kr0 = ((const float4*)src)[0]; kr1 = ((const float4*)src)[1];
      kr2 = ((const float4*)src)[2]; kr3 = ((const float4*)src)[3];
      const unsigned short* s0 = V + (tokbase + kb2 + vk0) * DIMC + col0 + vd0;
      const unsigned short* s1 = s0 + DIMC;
      va0 = *(const bf16x8*)(s0); va1 = *(const bf16x8*)(s0 + 8);
      vb0 = *(const bf16x8*)(s1); vb1 = *(const bf16x8*)(s1 + 8);
    }

    f32x4 sacc[2][4];
    #pragma unroll
    for (int qq = 0; qq < 2; qq++)
      #pragma unroll
      for (int nt = 0; nt < 4; nt++) sacc[qq][nt] = (f32x4){0.f, 0.f, 0.f, 0.f};
    #pragma unroll
    for (int kc = 0; kc < 4; kc++) {
      bf16x8 bk[4];
      #pragma unroll
      for (int nt = 0; nt < 4; nt++)
        bk[nt] = *(const bf16x8*)&SU[(nt * 16 + c) * 136 + kc * 32 + g * 8];
      #pragma unroll
      for (int qq = 0; qq < 2; qq++)
        #pragma unroll
        for (int nt = 0; nt < 4; nt++)
          sacc[qq][nt] = __builtin_amdgcn_mfma_f32_16x16x32_bf16(
              qf[qq][kc], bk[nt], sacc[qq][nt], 0, 0, 0);
    }
    __syncthreads();   // C: Ks reads done before Ps overwrites SU

    #pragma unroll
    for (int qq = 0; qq < 2; qq++)
      #pragma unroll
      for (int r = 0; r < 4; r++) {
        const int qg = qbase + qw + qq * 16 + g * 4 + r;
        #pragma unroll
        for (int nt = 0; nt < 4; nt++) {
          const int kg = kb + nt * 16 + c;
          const float sv = sacc[qq][nt][r] * SC - FA_M;
          const float p = (kg > qg) ? 0.0f : __expf(sv);
          lpart[qq][r] += p;
          SU[(wave * 32 + qq * 16 + g * 4 + r) * 72 + nt * 16 + c] = f2b(p);
        }
      }

    #pragma unroll
    for (int kc = 0; kc < 2; kc++) {
      bf16x8 pb[2];
      #pragma unroll
      for (int qq = 0; qq < 2; qq++)
        pb[qq] = *(const bf16x8*)&SU[(wave * 32 + qq * 16 + c) * 72 + kc * 32 + g * 8];
      #pragma unroll
      for (int dt = 0; dt < 8; dt++) {
        bf16x8 va = *(const bf16x8*)&VT[(dt * 16 + c) * 72 + kc * 32 + g * 8];
        #pragma unroll
        for (int qq = 0; qq < 2; qq++)
          od[dt][qq] = __builtin_amdgcn_mfma_f32_16x16x32_bf16(
              va, pb[qq], od[dt][qq], 0, 0, 0);
      }
    }
  }

  #pragma unroll
  for (int qq = 0; qq < 2; qq++)
    #pragma unroll
    for (int r = 0; r < 4; r++) {
      float l = lpart[qq][r];
      #pragma unroll
      for (int off = 1; off < 16; off <<= 1) l += __shfl_xor(l, off);
      lpart[qq][r] = l;
    }
  __syncthreads();
  if (c == 0) {
    #pragma unroll
    for (int qq = 0; qq < 2; qq++)
      #pragma unroll
      for (int r = 0; r < 4; r++)
        red[wave][qq * 16 + g * 4 + r] = 1.0f / lpart[qq][r];
  }
  __syncthreads();
  #pragma unroll
  for (int qq = 0; qq < 2; qq++) {
    const float linv = red[wave][qq * 16 + c];
    unsigned short* yp =
        Y + (tokbase + qbase + qw + qq * 16 + c) * DIMC + col0;
    #pragma unroll
    for (int dt = 0; dt < 8; dt++)
      #pragma unroll
      for (int r = 0; r < 4; r++)
        yp[dt * 16 + g * 4 + r] = f2b(od[dt][qq][r] * linv);
  }
}

extern "C" void kernel_launch(void* const* d_in, const int* in_sizes, int n_in,
                              void* d_out, int out_size, void* d_ws, size_t ws_size,
                              hipStream_t stream)
{
  const void* x  = d_in[0];
  const void* wq = d_in[1];
  const void* wk = d_in[2];
  const void* wv = d_in[3];
  const void* wo = d_in[4];
  float* out = (float*)d_out;

  char* ws = (char*)d_ws;
  const size_t MB = 1024 * 1024;
  unsigned short* wbuf = (unsigned short*)(ws + 0 * MB);   // 24 MB (QKV stacked)
  unsigned short* xb   = (unsigned short*)(ws + 24 * MB);  // 16 MB
  unsigned short* Qb   = (unsigned short*)(ws + 40 * MB);  // 16 MB
  unsigned short* Kb   = (unsigned short*)(ws + 56 * MB);  // 16 MB
  unsigned short* Vb   = (unsigned short*)(ws + 72 * MB);  // 16 MB
  unsigned short* wob  = (unsigned short*)(ws + 88 * MB);  // 8 MB (if room)
  unsigned short* Yb   = xb;   // x dead after QKV projection; alias.

  const int wo_in_prep = (ws_size >= 97 * MB) ? 1 : 0;

  prep<<<dim3(2048, wo_in_prep ? 5 : 4), 256, 0, stream>>>(
      x, wq, wk, wv, wo, xb, wbuf, wob);
  gemm256_qkv<<<dim3(16, 24), 512, 0, stream>>>(xb, wbuf, Qb, Kb, Vb);
  rope_kernel<<<dim3(4096), 256, 0, stream>>>(Qb, Kb);
  fattn<<<dim3(512), 256, 0, stream>>>(Qb, Kb, Vb, Yb);
  const unsigned short* wo_b;
  if (wo_in_prep) {
    wo_b = wob;
  } else {
    dequant_auto<<<dim3(8192), 256, 0, stream>>>(wo, x, wbuf);
    wo_b = wbuf;
  }
  gemm8_bt<<<dim3(16, 16), 512, 0, stream>>>(Yb, wo_b, out, DIMC, DIMC);
}